// Round 1
// baseline (516.951 us; speedup 1.0000x reference)
//
#include <hip/hip_runtime.h>
#include <cstdint>
#include <cstddef>

#define BB 8
#define NN 2048
#define FD 256
#define KK 205      // int(2048*0.1)+1
#define CAP 96      // max nnz per adj row (mean ~41, P(>96) ~ 1e-15)
#define SELCAP 256  // max selected columns (nsel ~205; clamped if ever exceeded)

typedef float f4 __attribute__((ext_vector_type(4)));  // native vec4: valid for nontemporal builtins

// Packed ELL entry: x = column index, y = __float_as_int(value)
// Packed sel entry: x = __float_as_int(dg*cutA), y = selidx

// ---------- fused: ELL sparsify of adj (ballot compaction) + row sum + dg + y = x.W + dgy ----------
__global__ __launch_bounds__(256) void k_spy(const float* __restrict__ adj, const float* __restrict__ x,
                                             const float* __restrict__ W, int2* __restrict__ ell,
                                             int* __restrict__ ell_cnt, float* __restrict__ dg,
                                             float* __restrict__ dgy) {
  int r = blockIdx.x;  // b*NN + n
  const f4* arow4 = (const f4*)(adj + (size_t)r * NN);
  int t = threadIdx.x;
  int lane = t & 63, wv = t >> 6;
  __shared__ int counter;
  __shared__ float wsum[4], wy[4];
  if (t == 0) counter = 0;
  __syncthreads();
  size_t base = (size_t)r * CAP;
  unsigned long long lmask = (1ull << lane) - 1;   // lane<=63 -> no UB
  float ls = 0.f;
#pragma unroll
  for (int j = 0; j < 2; ++j) {
    int i4 = t + j * 256;
    f4 v = __builtin_nontemporal_load(&arow4[i4]);  // read-once stream: don't pollute L2
    int m0 = i4 * 4;
#pragma unroll
    for (int c = 0; c < 4; ++c) {
      float val = v[c];
      unsigned long long mk = __ballot(val != 0.f);
      if (mk) {
        int wbase = 0;
        if (lane == 0) wbase = atomicAdd(&counter, (int)__popcll(mk));
        wbase = __shfl(wbase, 0);                  // one atomic per wave per component
        if (val != 0.f) {
          int p = wbase + (int)__popcll(mk & lmask);
          if (p < CAP) ell[base + p] = make_int2(m0 + c, __float_as_int(val));
        }
      }
      ls += val;                                   // val==0 adds nothing
    }
  }
#pragma unroll
  for (int off = 32; off > 0; off >>= 1) ls += __shfl_down(ls, off);
  if (lane == 0) wsum[wv] = ls;
  float xv = x[(size_t)r * FD + t] * W[t];
#pragma unroll
  for (int off = 32; off > 0; off >>= 1) xv += __shfl_down(xv, off);
  if (lane == 0) wy[wv] = xv;
  __syncthreads();
  if (t == 0) {
    int tot = counter; if (tot > CAP) tot = CAP;
    ell_cnt[r] = tot;
    float rs = wsum[0] + wsum[1] + wsum[2] + wsum[3];
    float d = 1.0f / sqrtf(1.0f + rs);  // A_hat row sum = 1 + adj row sum >= 1 (clip is a no-op)
    dg[r] = d;
    dgy[r] = d * (wy[0] + wy[1] + wy[2] + wy[3]);  // fused product: one gather in k_alpha
  }
}

// ---------- alpha[b,n] = sigmoid((dg[n]*(sum_m A_hat[n,m]*dg[m]*y[m]) + b)^2) ----------
__global__ __launch_bounds__(256) void k_alpha(const int2* __restrict__ ell, const int* __restrict__ ell_cnt,
                                               const float* __restrict__ dg, const float* __restrict__ dgy,
                                               const float* __restrict__ bptr, float* __restrict__ alpha) {
  int lane = threadIdx.x & 63, wv = threadIdx.x >> 6;
  int r = blockIdx.x * 4 + wv;
  int b = r / NN;
  int cnt = ell_cnt[r];
  size_t base = (size_t)r * CAP;
  const float* gyb = dgy + (size_t)b * NN;
  float acc = 0.f;
  for (int j = lane; j < cnt; j += 64) {
    int2 e = ell[base + j];
    acc += __int_as_float(e.y) * gyb[e.x];        // single gather per entry
  }
#pragma unroll
  for (int off = 32; off > 0; off >>= 1) acc += __shfl_down(acc, off);
  if (lane == 0) {
    float dgn = dg[r];
    float z = dgn * (acc + dgy[r]) + bptr[0];     // diag: dgn * (dgn*y[r]) = dgn * dgy[r]
    float t2 = z * z;
    alpha[r] = 1.0f / (1.0f + expf(-t2));
  }
}

// ---------- rank-based exact top-K (ties -> smaller index first, like lax.top_k) ----------
__global__ __launch_bounds__(256) void k_rank(const float* __restrict__ alpha, float* __restrict__ cutv,
                                              float* __restrict__ out_topi, int* __restrict__ sel_cnt) {
  __shared__ unsigned int keys[NN];  // 8 KiB: alpha bits (alpha >= 0.5 > 0 -> bit order == value order)
  int b = blockIdx.x & 7;
  int chunk = blockIdx.x >> 3;
  int t = threadIdx.x;
  if (chunk == 0 && t == 0) sel_cnt[b] = 0;   // replaces the sel_cnt memset dispatch
  const float* ab = alpha + (size_t)b * NN;
  for (int i = t; i < NN; i += 256) keys[i] = __float_as_uint(ab[i]);
  __syncthreads();
  int i = chunk * 256 + t;
  unsigned int ai = keys[i];
  int rank = 0;
  const uint4* k4 = (const uint4*)keys;       // broadcast reads: all lanes same addr, conflict-free
#pragma unroll 4
  for (int j4 = 0; j4 < NN / 4; ++j4) {
    uint4 v = k4[j4];
    int j = j4 * 4;
    rank += (v.x > ai) || (v.x == ai && (j + 0) < i);
    rank += (v.y > ai) || (v.y == ai && (j + 1) < i);
    rank += (v.z > ai) || (v.z == ai && (j + 2) < i);
    rank += (v.w > ai) || (v.w == ai && (j + 3) < i);
  }
  if (rank < KK) out_topi[(size_t)b * KK + rank] = (float)i;
  if (rank == KK - 1) cutv[b] = __uint_as_float(ai);
}

// ---------- cut_alpha + selected compaction + packed {dgca, selidx} ----------
__global__ __launch_bounds__(256) void k_selcut(const float* __restrict__ alpha, const float* __restrict__ cutv,
                                                const float* __restrict__ dg, int2* __restrict__ seldg,
                                                int* __restrict__ sel_list, int* __restrict__ sel_cnt) {
  int r = blockIdx.x * 256 + threadIdx.x;
  int b = r / NN, n = r % NN;
  float ca = fmaxf(alpha[r] + 1e-7f - cutv[b], 0.0f);
  int s = -1;
  if (ca > 0.f) {
    s = atomicAdd(&sel_cnt[b], 1);
    if (s < SELCAP) sel_list[b * SELCAP + s] = n; else s = -1;
  }
  seldg[r] = make_int2(__float_as_int(dg[r] * ca), s);  // one 8B gather serves k_sbuild
}

// ---------- fused: normalized S row -> dense output row (nt) + compact Sc row + dginv ----------
// Reworked: 2 barriers instead of 4 (inv computed redundantly by all threads; diagonal folded
// branchlessly into the store phase), Sc store trimmed to t < nsel (k_M/k_epi2 never read beyond).
__global__ __launch_bounds__(256) void k_sbuild(const int2* __restrict__ ell, const int* __restrict__ ell_cnt,
                                                const float* __restrict__ dg, const int2* __restrict__ seldg,
                                                const int* __restrict__ sel_cnt,
                                                float* __restrict__ dginv,
                                                float* __restrict__ Sc, float* __restrict__ outS) {
  __shared__ float row[NN];        // 8 KiB dense S row
  __shared__ float scrow[SELCAP];  // 1 KiB compact row
  __shared__ int   sidx[CAP];      // column m
  __shared__ int   ssel[CAP];      // selidx of m
  __shared__ float sterm[CAP];
  __shared__ float wred[4];
  int r = blockIdx.x;  // b*NN + n
  int b = r >> 11;
  int n = r & (NN - 1);
  int t = threadIdx.x;
  int lane = t & 63, wv = t >> 6;
#pragma unroll
  for (int j = 0; j < NN / 256; ++j) row[t + j * 256] = 0.f;
  if (t < SELCAP) scrow[t] = 0.f;
  int cnt = ell_cnt[r];
  size_t base = (size_t)r * CAP;
  float dgn = dg[r];
  const int2* sdb = seldg + (size_t)b * NN;
  float part = 0.f;
  for (int j = t; j < cnt; j += 256) {
    int2 e = ell[base + j];
    int2 sd = sdb[e.x];                               // single 8B gather: {dg*cutA, selidx}
    float term = dgn * __int_as_float(e.y) * __int_as_float(sd.x);
    sidx[j] = e.x; ssel[j] = sd.y; sterm[j] = term;
    part += term;
  }
#pragma unroll
  for (int off = 32; off > 0; off >>= 1) part += __shfl_down(part, off);
  if (lane == 0) wred[wv] = part;
  __syncthreads();                                    // wred + sterm/sidx/ssel + row-zero all visible
  int2 sdn = sdb[n];                                  // broadcast load (same addr all threads)
  float diag = dgn * __int_as_float(sdn.x);           // dgn * dg[n]*cutA[n]
  float rho = wred[0] + wred[1] + wred[2] + wred[3] + diag;  // L1 row sum (all >= 0)
  float inv = (cnt > 0) ? (1.0f / fmaxf(rho, 1e-12f)) : 0.f; // mask (adj rowsum>0 <=> cnt>0) * normalize
  float dv = diag * inv;
  if (t == 0) dginv[r] = dgn * inv;                   // fused product: one gather in k_epi2
  for (int j = t; j < cnt; j += 256) {                // distinct m per j -> no conflicts
    float v = sterm[j] * inv;
    row[sidx[j]] = v;
    int si = ssel[j];
    if (si >= 0) scrow[si] = v;
  }
  __syncthreads();                                    // scatter complete before store reads
  int nsel = sel_cnt[b]; if (nsel > SELCAP) nsel = SELCAP;
  f4* dst = (f4*)(outS + (size_t)r * NN);
  const f4* src = (const f4*)row;
#pragma unroll
  for (int j = 0; j < NN / 4 / 256; ++j) {
    int idx = t + j * 256;
    f4 v = src[idx];
    int b4 = idx * 4;                                 // fold diag in branchlessly (handles adj self-loop: +=)
    v[0] += (b4 + 0 == n) ? dv : 0.f;
    v[1] += (b4 + 1 == n) ? dv : 0.f;
    v[2] += (b4 + 2 == n) ? dv : 0.f;
    v[3] += (b4 + 3 == n) ? dv : 0.f;
    __builtin_nontemporal_store(v, &dst[idx]);        // stream S out, keep Sc in L2
  }
  if (t < nsel) {
    float sv = scrow[t];
    if (t == sdn.y) sv += dv;                         // diagonal lands in compact row iff n selected
    Sc[(size_t)r * SELCAP + t] = sv;
  }
}

// ---------- M[n, :] = sum_k adj[n,k] * Sc[k, :]  (dense-compact; batch pinned to XCD) ----------
// 8-way MLP (cnt ~41 -> one full pass) + columns trimmed to t < nsel (epi2 reads only those).
__global__ __launch_bounds__(256) void k_M(const int2* __restrict__ ell, const int* __restrict__ ell_cnt,
                                           const int* __restrict__ sel_cnt,
                                           const float* __restrict__ Sc, float* __restrict__ Mmat) {
  int b = blockIdx.x & 7;           // batch -> XCD: Sc[b] (2 MB) stays L2-resident
  int n = blockIdx.x >> 3;
  int r = b * NN + n;
  int t = threadIdx.x;
  __shared__ int srk[CAP];
  __shared__ float sav[CAP];
  int cnt = ell_cnt[r];
  size_t base = (size_t)r * CAP;
  for (int e = t; e < cnt; e += 256) {
    int2 p = ell[base + e];
    srk[e] = b * NN + p.x;
    sav[e] = __int_as_float(p.y);
  }
  __syncthreads();
  int nsel = sel_cnt[b]; if (nsel > SELCAP) nsel = SELCAP;
  if (t >= nsel) return;            // no barriers after this point; trims ~20% of gather traffic
  float a0 = 0.f, a1 = 0.f, a2 = 0.f, a3 = 0.f, a4 = 0.f, a5 = 0.f, a6 = 0.f, a7 = 0.f;
  int e = 0;
  for (; e + 8 <= cnt; e += 8) {    // 8 loads in flight per iteration
    a0 += sav[e + 0] * Sc[(size_t)srk[e + 0] * SELCAP + t];
    a1 += sav[e + 1] * Sc[(size_t)srk[e + 1] * SELCAP + t];
    a2 += sav[e + 2] * Sc[(size_t)srk[e + 2] * SELCAP + t];
    a3 += sav[e + 3] * Sc[(size_t)srk[e + 3] * SELCAP + t];
    a4 += sav[e + 4] * Sc[(size_t)srk[e + 4] * SELCAP + t];
    a5 += sav[e + 5] * Sc[(size_t)srk[e + 5] * SELCAP + t];
    a6 += sav[e + 6] * Sc[(size_t)srk[e + 6] * SELCAP + t];
    a7 += sav[e + 7] * Sc[(size_t)srk[e + 7] * SELCAP + t];
  }
  for (; e < cnt; ++e) a0 += sav[e] * Sc[(size_t)srk[e] * SELCAP + t];
  Mmat[(size_t)r * SELCAP + t] = ((a0 + a1) + (a2 + a3)) + ((a4 + a5) + (a6 + a7));
}

// ---------- full-grid epilogue: every row of xc and coarse written (no memset needed) ----------
// Reworked: branchless 4-way MLP gather loop (8 loads in flight); Mmat loads gated to t < nsel.
__global__ __launch_bounds__(256) void k_epi2(const float* __restrict__ x, const int2* __restrict__ ell,
                                              const int* __restrict__ ell_cnt, const int2* __restrict__ seldg,
                                              const float* __restrict__ dginv, const int* __restrict__ sel_list,
                                              const int* __restrict__ sel_cnt, const float* __restrict__ Mmat,
                                              float* __restrict__ xc, float* __restrict__ coarse) {
  int b = blockIdx.x & 7;           // batch -> XCD: x[b], Mmat[b] (2 MB each) stay L2-resident
  int m = blockIdx.x >> 3;
  int rm = b * NN + m;
  int t = threadIdx.x;
  __shared__ float row[NN];         // 8 KiB coarse row
  __shared__ int cn[CAP + 1];
  __shared__ float cw[CAP + 1];
  int2 sd_m = seldg[rm];
  bool sel = sd_m.y >= 0;           // block-uniform
  if (!sel) {                       // ~90% of rows: stream zeros, no LDS at all
    f4 z = (f4)(0.f);
    if (t < FD / 4) __builtin_nontemporal_store(z, &((f4*)(xc + (size_t)rm * FD))[t]);
    f4* dco = (f4*)(coarse + (size_t)rm * NN);
    __builtin_nontemporal_store(z, &dco[t]);
    __builtin_nontemporal_store(z, &dco[t + 256]);
    return;
  }
  int nsel = sel_cnt[b]; if (nsel > SELCAP) nsel = SELCAP;
  int cnt = ell_cnt[rm];
#pragma unroll
  for (int j = 0; j < NN / 256; ++j) row[t + j * 256] = 0.f;
  {
    float dgca_m = __int_as_float(sd_m.x);           // dg[m]*cutA[m]
    // column m of S == row m of adj (exact symmetry) plus the diagonal (+1) entry
    for (int j = t; j <= cnt; j += 256) {
      if (j < cnt) {
        int2 e = ell[(size_t)rm * CAP + j];
        cn[j] = b * NN + e.x;
        cw[j] = __int_as_float(e.y) * dgca_m * dginv[b * NN + e.x];  // single gather per entry
      } else {
        cn[j] = rm;
        cw[j] = dgca_m * dginv[rm];
      }
    }
  }
  __syncthreads();
  bool act = t < nsel;              // only these lanes' aco is ever consumed
  float axc = 0.f, aco = 0.f;
  int tot = cnt + 1;
  int e = 0;
  for (; e + 4 <= tot; e += 4) {    // 4-way MLP: up to 8 independent loads in flight
    int r0 = cn[e + 0], r1 = cn[e + 1], r2 = cn[e + 2], r3 = cn[e + 3];
    float w0 = cw[e + 0], w1 = cw[e + 1], w2 = cw[e + 2], w3 = cw[e + 3];
    float x0 = x[(size_t)r0 * FD + t];
    float x1 = x[(size_t)r1 * FD + t];
    float x2 = x[(size_t)r2 * FD + t];
    float x3 = x[(size_t)r3 * FD + t];
    float m0 = 0.f, m1 = 0.f, m2 = 0.f, m3 = 0.f;
    if (act) {
      m0 = Mmat[(size_t)r0 * SELCAP + t];
      m1 = Mmat[(size_t)r1 * SELCAP + t];
      m2 = Mmat[(size_t)r2 * SELCAP + t];
      m3 = Mmat[(size_t)r3 * SELCAP + t];
    }
    axc += w0 * x0 + w1 * x1 + w2 * x2 + w3 * x3;
    aco += w0 * m0 + w1 * m1 + w2 * m2 + w3 * m3;
  }
  for (; e < tot; ++e) {
    int rn = cn[e];
    float w = cw[e];
    axc += w * x[(size_t)rn * FD + t];
    if (act) aco += w * Mmat[(size_t)rn * SELCAP + t];
  }
  if (act) row[sel_list[b * SELCAP + t]] = floorf(aco * 10000.0f) / 10000.0f;
  __builtin_nontemporal_store(axc, &xc[(size_t)rm * FD + t]);
  __syncthreads();
  f4* dst = (f4*)(coarse + (size_t)rm * NN);
  const f4* src = (const f4*)row;
#pragma unroll
  for (int j = 0; j < NN / 4 / 256; ++j)
    __builtin_nontemporal_store(src[t + j * 256], &dst[t + j * 256]);  // stream coarse out
}

extern "C" void kernel_launch(void* const* d_in, const int* in_sizes, int n_in,
                              void* d_out, int out_size, void* d_ws, size_t ws_size,
                              hipStream_t stream) {
  (void)in_sizes; (void)n_in; (void)ws_size; (void)out_size;
  const float* x = (const float*)d_in[0];
  const float* adj = (const float*)d_in[1];
  const float* W = (const float*)d_in[2];
  const float* bptr = (const float*)d_in[3];

  float* out = (float*)d_out;
  const size_t XC_SZ = (size_t)BB * NN * FD;   // 4,194,304
  const size_t CO_SZ = (size_t)BB * NN * NN;   // 33,554,432
  const size_t S_SZ  = (size_t)BB * NN * NN;   // 33,554,432
  float* out_xc = out;
  float* out_co = out + XC_SZ;
  float* out_S  = out + XC_SZ + CO_SZ;
  float* out_ti = out + XC_SZ + CO_SZ + S_SZ;  // topi as float (written fully by k_rank)

  char* w = (char*)d_ws;
  int2*  ell     = (int2*)w;  w += (size_t)BB * NN * CAP * 8;
  float* Sc      = (float*)w; w += (size_t)BB * NN * SELCAP * 4;
  float* Mmat    = (float*)w; w += (size_t)BB * NN * SELCAP * 4;
  int2*  seldg   = (int2*)w;  w += (size_t)BB * NN * 8;
  int*   ell_cnt = (int*)w;   w += (size_t)BB * NN * 4;
  float* dg      = (float*)w; w += (size_t)BB * NN * 4;
  float* dgy     = (float*)w; w += (size_t)BB * NN * 4;
  float* alpha   = (float*)w; w += (size_t)BB * NN * 4;
  float* dginv   = (float*)w; w += (size_t)BB * NN * 4;
  float* cutv    = (float*)w; w += (size_t)BB * 4;
  int*   sel_cnt = (int*)w;   w += (size_t)BB * 4;
  int*   sel_list= (int*)w;   w += (size_t)BB * SELCAP * 4;

  // every output byte written by kernels: xc+coarse by k_epi2, S by k_sbuild, topi by k_rank
  k_spy<<<BB * NN, 256, 0, stream>>>(adj, x, W, ell, ell_cnt, dg, dgy);
  k_alpha<<<BB * NN / 4, 256, 0, stream>>>(ell, ell_cnt, dg, dgy, bptr, alpha);
  k_rank<<<BB * 8, 256, 0, stream>>>(alpha, cutv, out_ti, sel_cnt);
  k_selcut<<<BB * NN / 256, 256, 0, stream>>>(alpha, cutv, dg, seldg, sel_list, sel_cnt);
  k_sbuild<<<BB * NN, 256, 0, stream>>>(ell, ell_cnt, dg, seldg, sel_cnt, dginv, Sc, out_S);
  k_M<<<BB * NN, 256, 0, stream>>>(ell, ell_cnt, sel_cnt, Sc, Mmat);
  k_epi2<<<BB * NN, 256, 0, stream>>>(x, ell, ell_cnt, seldg, dginv,
                                      sel_list, sel_cnt, Mmat, out_xc, out_co);
}

// Round 2
// 506.164 us; speedup vs baseline: 1.0213x; 1.0213x over previous
//
#include <hip/hip_runtime.h>
#include <cstdint>
#include <cstddef>

#define BB 8
#define NN 2048
#define FD 256
#define KK 205      // int(2048*0.1)+1
#define CAP 96      // max nnz per adj row (mean ~41, P(>96) ~ 1e-15)
#define SELCAP 256  // max selected columns (nsel ~205; clamped if ever exceeded)

typedef float f4 __attribute__((ext_vector_type(4)));  // native vec4: valid for nontemporal builtins

// Packed ELL entry: x = column index, y = __float_as_int(value)
// Packed sel entry: x = __float_as_int(dg*cutA), y = selidx

// ---------- fused: ELL sparsify of adj (ballot compaction) + row sum + dg + y = x.W + dgy ----------
__global__ __launch_bounds__(256) void k_spy(const float* __restrict__ adj, const float* __restrict__ x,
                                             const float* __restrict__ W, int2* __restrict__ ell,
                                             int* __restrict__ ell_cnt, float* __restrict__ dg,
                                             float* __restrict__ dgy) {
  int r = blockIdx.x;  // b*NN + n
  const f4* arow4 = (const f4*)(adj + (size_t)r * NN);
  int t = threadIdx.x;
  int lane = t & 63, wv = t >> 6;
  __shared__ int counter;
  __shared__ float wsum[4], wy[4];
  if (t == 0) counter = 0;
  __syncthreads();
  size_t base = (size_t)r * CAP;
  unsigned long long lmask = (1ull << lane) - 1;   // lane<=63 -> no UB
  float ls = 0.f;
#pragma unroll
  for (int j = 0; j < 2; ++j) {
    int i4 = t + j * 256;
    f4 v = __builtin_nontemporal_load(&arow4[i4]);  // read-once stream: don't pollute L2
    int m0 = i4 * 4;
#pragma unroll
    for (int c = 0; c < 4; ++c) {
      float val = v[c];
      unsigned long long mk = __ballot(val != 0.f);
      if (mk) {
        int wbase = 0;
        if (lane == 0) wbase = atomicAdd(&counter, (int)__popcll(mk));
        wbase = __shfl(wbase, 0);                  // one atomic per wave per component
        if (val != 0.f) {
          int p = wbase + (int)__popcll(mk & lmask);
          if (p < CAP) ell[base + p] = make_int2(m0 + c, __float_as_int(val));
        }
      }
      ls += val;                                   // val==0 adds nothing
    }
  }
#pragma unroll
  for (int off = 32; off > 0; off >>= 1) ls += __shfl_down(ls, off);
  if (lane == 0) wsum[wv] = ls;
  float xv = x[(size_t)r * FD + t] * W[t];
#pragma unroll
  for (int off = 32; off > 0; off >>= 1) xv += __shfl_down(xv, off);
  if (lane == 0) wy[wv] = xv;
  __syncthreads();
  if (t == 0) {
    int tot = counter; if (tot > CAP) tot = CAP;
    ell_cnt[r] = tot;
    float rs = wsum[0] + wsum[1] + wsum[2] + wsum[3];
    float d = 1.0f / sqrtf(1.0f + rs);  // A_hat row sum = 1 + adj row sum >= 1 (clip is a no-op)
    dg[r] = d;
    dgy[r] = d * (wy[0] + wy[1] + wy[2] + wy[3]);  // fused product: one gather in k_alpha
  }
}

// ---------- alpha[b,n] = sigmoid((dg[n]*(sum_m A_hat[n,m]*dg[m]*y[m]) + b)^2) ----------
__global__ __launch_bounds__(256) void k_alpha(const int2* __restrict__ ell, const int* __restrict__ ell_cnt,
                                               const float* __restrict__ dg, const float* __restrict__ dgy,
                                               const float* __restrict__ bptr, float* __restrict__ alpha) {
  int lane = threadIdx.x & 63, wv = threadIdx.x >> 6;
  int r = blockIdx.x * 4 + wv;
  int b = r / NN;
  int cnt = ell_cnt[r];
  size_t base = (size_t)r * CAP;
  const float* gyb = dgy + (size_t)b * NN;
  float acc = 0.f;
  for (int j = lane; j < cnt; j += 64) {
    int2 e = ell[base + j];
    acc += __int_as_float(e.y) * gyb[e.x];        // single gather per entry
  }
#pragma unroll
  for (int off = 32; off > 0; off >>= 1) acc += __shfl_down(acc, off);
  if (lane == 0) {
    float dgn = dg[r];
    float z = dgn * (acc + dgy[r]) + bptr[0];     // diag: dgn * (dgn*y[r]) = dgn * dgy[r]
    float t2 = z * z;
    alpha[r] = 1.0f / (1.0f + expf(-t2));
  }
}

// ---------- rank-based exact top-K (ties -> smaller index first, like lax.top_k) ----------
__global__ __launch_bounds__(256) void k_rank(const float* __restrict__ alpha, float* __restrict__ cutv,
                                              float* __restrict__ out_topi, int* __restrict__ sel_cnt) {
  __shared__ unsigned int keys[NN];  // 8 KiB: alpha bits (alpha >= 0.5 > 0 -> bit order == value order)
  int b = blockIdx.x & 7;
  int chunk = blockIdx.x >> 3;
  int t = threadIdx.x;
  if (chunk == 0 && t == 0) sel_cnt[b] = 0;   // replaces the sel_cnt memset dispatch
  const float* ab = alpha + (size_t)b * NN;
  for (int i = t; i < NN; i += 256) keys[i] = __float_as_uint(ab[i]);
  __syncthreads();
  int i = chunk * 256 + t;
  unsigned int ai = keys[i];
  int rank = 0;
  const uint4* k4 = (const uint4*)keys;       // broadcast reads: all lanes same addr, conflict-free
#pragma unroll 4
  for (int j4 = 0; j4 < NN / 4; ++j4) {
    uint4 v = k4[j4];
    int j = j4 * 4;
    rank += (v.x > ai) || (v.x == ai && (j + 0) < i);
    rank += (v.y > ai) || (v.y == ai && (j + 1) < i);
    rank += (v.z > ai) || (v.z == ai && (j + 2) < i);
    rank += (v.w > ai) || (v.w == ai && (j + 3) < i);
  }
  if (rank < KK) out_topi[(size_t)b * KK + rank] = (float)i;
  if (rank == KK - 1) cutv[b] = __uint_as_float(ai);
}

// ---------- cut_alpha + selected compaction + packed {dgca, selidx} ----------
__global__ __launch_bounds__(256) void k_selcut(const float* __restrict__ alpha, const float* __restrict__ cutv,
                                                const float* __restrict__ dg, int2* __restrict__ seldg,
                                                int* __restrict__ sel_list, int* __restrict__ sel_cnt) {
  int r = blockIdx.x * 256 + threadIdx.x;
  int b = r / NN, n = r % NN;
  float ca = fmaxf(alpha[r] + 1e-7f - cutv[b], 0.0f);
  int s = -1;
  if (ca > 0.f) {
    s = atomicAdd(&sel_cnt[b], 1);
    if (s < SELCAP) sel_list[b * SELCAP + s] = n; else s = -1;
  }
  seldg[r] = make_int2(__float_as_int(dg[r] * ca), s);  // one 8B gather serves downstream
}

// ---------- wave-per-row Sc builder + dginv (no __syncthreads; dense-S write moved to k_Ms) ----------
__global__ __launch_bounds__(256) void k_sc(const int2* __restrict__ ell, const int* __restrict__ ell_cnt,
                                            const float* __restrict__ dg, const int2* __restrict__ seldg,
                                            const int* __restrict__ sel_cnt,
                                            float* __restrict__ dginv, float* __restrict__ Sc) {
  int lane = threadIdx.x & 63, wv = threadIdx.x >> 6;
  int r = blockIdx.x * 4 + wv;       // one wave per row
  int b = r >> 11, n = r & (NN - 1);
  __shared__ float scrow[4][SELCAP]; // per-wave slice: wave-coherent LDS, no barrier needed
  float* sc = scrow[wv];
#pragma unroll
  for (int j = lane; j < SELCAP; j += 64) sc[j] = 0.f;
  int cnt = ell_cnt[r];
  size_t base = (size_t)r * CAP;
  float dgn = dg[r];
  const int2* sdb = seldg + (size_t)b * NN;
  // CAP=96 <= 128: at most 2 entries per lane
  float t0 = 0.f, t1 = 0.f;
  int s0 = -1, s1 = -1;
  if (lane < cnt) {
    int2 e = ell[base + lane];
    int2 sd = sdb[e.x];
    t0 = dgn * __int_as_float(e.y) * __int_as_float(sd.x);  // same mult order as before
    s0 = sd.y;
  }
  if (lane + 64 < cnt) {
    int2 e = ell[base + lane + 64];
    int2 sd = sdb[e.x];
    t1 = dgn * __int_as_float(e.y) * __int_as_float(sd.x);
    s1 = sd.y;
  }
  float part = t0 + t1;
#pragma unroll
  for (int off = 32; off > 0; off >>= 1) part += __shfl_down(part, off);
  part = __shfl(part, 0);                             // broadcast row sum
  int2 sdn = sdb[n];                                  // same addr across wave -> broadcast load
  float diag = dgn * __int_as_float(sdn.x);           // dgn * dg[n]*cutA[n]
  float rho = part + diag;                            // L1 row sum (all >= 0)
  float inv = (cnt > 0) ? (1.0f / fmaxf(rho, 1e-12f)) : 0.f;  // mask * normalize
  if (lane == 0) dginv[r] = dgn * inv;                // fused product for k_Ms / k_epi2
  if (s0 >= 0) sc[s0] = t0 * inv;                     // in-wave LDS scatter
  if (s1 >= 0) sc[s1] = t1 * inv;
  int nsel = sel_cnt[b]; if (nsel > SELCAP) nsel = SELCAP;
  float dv = diag * inv;
  for (int p = lane; p < nsel; p += 64) {             // compiler orders ds_read after ds_write (same wave)
    float sv = sc[p];
    if (p == sdn.y) sv += dv;                         // diagonal lands in compact row iff n selected
    Sc[(size_t)r * SELCAP + p] = sv;
  }
}

// ---------- fused: M[n,:] = sum_k adj[n,k]*Sc[k,:]  AND dense S row -> out_S ----------
// The 134 MB S stream (pure sink) now overlaps the L2-bound Sc gathers instead of
// occupying its own serialized dispatch.
__global__ __launch_bounds__(256) void k_Ms(const int2* __restrict__ ell, const int* __restrict__ ell_cnt,
                                            const int* __restrict__ sel_cnt, const int2* __restrict__ seldg,
                                            const float* __restrict__ dginv, const float* __restrict__ Sc,
                                            float* __restrict__ Mmat, float* __restrict__ outS) {
  int b = blockIdx.x & 7;           // batch -> XCD: Sc[b] (~0.8 MB) stays L2-resident
  int n = blockIdx.x >> 3;
  int r = b * NN + n;
  int t = threadIdx.x;
  __shared__ float row[NN];         // 8 KiB dense S row
  __shared__ int srk[CAP];
  __shared__ float sav[CAP];
#pragma unroll
  for (int j = 0; j < NN / 256; ++j) row[t + j * 256] = 0.f;
  int cnt = ell_cnt[r];
  size_t base = (size_t)r * CAP;
  float dinv = dginv[r];            // dg[r] * inv_r  (0 if cnt==0 -> zero S row)
  const int2* sdb = seldg + (size_t)b * NN;
  for (int e = t; e < cnt; e += 256) {
    int2 p = ell[base + e];
    srk[e] = b * NN + p.x;
    float v = __int_as_float(p.y);
    sav[e] = v;
    row[p.x] = dinv * v * __int_as_float(sdb[p.x].x);  // distinct cols -> conflict-free scatter
  }
  __syncthreads();
  float dv = dinv * __int_as_float(sdb[n].x);          // diagonal S[n,n] contribution
  f4* dst = (f4*)(outS + (size_t)r * NN);
  const f4* src = (const f4*)row;
#pragma unroll
  for (int j = 0; j < NN / 4 / 256; ++j) {
    int idx = t + j * 256;
    f4 v = src[idx];
    int b4 = idx * 4;                                  // fold diag branchlessly (handles adj self-loop: +=)
    v[0] += (b4 + 0 == n) ? dv : 0.f;
    v[1] += (b4 + 1 == n) ? dv : 0.f;
    v[2] += (b4 + 2 == n) ? dv : 0.f;
    v[3] += (b4 + 3 == n) ? dv : 0.f;
    __builtin_nontemporal_store(v, &dst[idx]);         // stream S out; stores don't stall the gathers below
  }
  int nsel = sel_cnt[b]; if (nsel > SELCAP) nsel = SELCAP;
  if (t >= nsel) return;            // no barriers below; trims ~20% of gather traffic
  float a0 = 0.f, a1 = 0.f, a2 = 0.f, a3 = 0.f, a4 = 0.f, a5 = 0.f, a6 = 0.f, a7 = 0.f;
  int e = 0;
  for (; e + 8 <= cnt; e += 8) {    // 8 loads in flight per iteration
    a0 += sav[e + 0] * Sc[(size_t)srk[e + 0] * SELCAP + t];
    a1 += sav[e + 1] * Sc[(size_t)srk[e + 1] * SELCAP + t];
    a2 += sav[e + 2] * Sc[(size_t)srk[e + 2] * SELCAP + t];
    a3 += sav[e + 3] * Sc[(size_t)srk[e + 3] * SELCAP + t];
    a4 += sav[e + 4] * Sc[(size_t)srk[e + 4] * SELCAP + t];
    a5 += sav[e + 5] * Sc[(size_t)srk[e + 5] * SELCAP + t];
    a6 += sav[e + 6] * Sc[(size_t)srk[e + 6] * SELCAP + t];
    a7 += sav[e + 7] * Sc[(size_t)srk[e + 7] * SELCAP + t];
  }
  for (; e < cnt; ++e) a0 += sav[e] * Sc[(size_t)srk[e] * SELCAP + t];
  Mmat[(size_t)r * SELCAP + t] = ((a0 + a1) + (a2 + a3)) + ((a4 + a5) + (a6 + a7));
}

// ---------- full-grid epilogue: every row of xc and coarse written (no memset needed) ----------
__global__ __launch_bounds__(256) void k_epi2(const float* __restrict__ x, const int2* __restrict__ ell,
                                              const int* __restrict__ ell_cnt, const int2* __restrict__ seldg,
                                              const float* __restrict__ dginv, const int* __restrict__ sel_list,
                                              const int* __restrict__ sel_cnt, const float* __restrict__ Mmat,
                                              float* __restrict__ xc, float* __restrict__ coarse) {
  int b = blockIdx.x & 7;           // batch -> XCD: x[b], Mmat[b] (~2 MB each) stay L2-resident
  int m = blockIdx.x >> 3;
  int rm = b * NN + m;
  int t = threadIdx.x;
  __shared__ float row[NN];         // 8 KiB coarse row
  __shared__ int cn[CAP + 1];
  __shared__ float cw[CAP + 1];
  int2 sd_m = seldg[rm];
  bool sel = sd_m.y >= 0;           // block-uniform
  if (!sel) {                       // ~90% of rows: stream zeros, no LDS at all
    f4 z = (f4)(0.f);
    if (t < FD / 4) __builtin_nontemporal_store(z, &((f4*)(xc + (size_t)rm * FD))[t]);
    f4* dco = (f4*)(coarse + (size_t)rm * NN);
    __builtin_nontemporal_store(z, &dco[t]);
    __builtin_nontemporal_store(z, &dco[t + 256]);
    return;
  }
  int nsel = sel_cnt[b]; if (nsel > SELCAP) nsel = SELCAP;
  int cnt = ell_cnt[rm];
#pragma unroll
  for (int j = 0; j < NN / 256; ++j) row[t + j * 256] = 0.f;
  {
    float dgca_m = __int_as_float(sd_m.x);           // dg[m]*cutA[m]
    // column m of S == row m of adj (exact symmetry) plus the diagonal (+1) entry
    for (int j = t; j <= cnt; j += 256) {
      if (j < cnt) {
        int2 e = ell[(size_t)rm * CAP + j];
        cn[j] = b * NN + e.x;
        cw[j] = __int_as_float(e.y) * dgca_m * dginv[b * NN + e.x];  // single gather per entry
      } else {
        cn[j] = rm;
        cw[j] = dgca_m * dginv[rm];
      }
    }
  }
  __syncthreads();
  bool act = t < nsel;              // only these lanes' aco is ever consumed
  float axc = 0.f, aco = 0.f;
  int tot = cnt + 1;
  int e = 0;
  for (; e + 4 <= tot; e += 4) {    // 4-way MLP: up to 8 independent loads in flight
    int r0 = cn[e + 0], r1 = cn[e + 1], r2 = cn[e + 2], r3 = cn[e + 3];
    float w0 = cw[e + 0], w1 = cw[e + 1], w2 = cw[e + 2], w3 = cw[e + 3];
    float x0 = x[(size_t)r0 * FD + t];
    float x1 = x[(size_t)r1 * FD + t];
    float x2 = x[(size_t)r2 * FD + t];
    float x3 = x[(size_t)r3 * FD + t];
    float m0 = 0.f, m1 = 0.f, m2 = 0.f, m3 = 0.f;
    if (act) {
      m0 = Mmat[(size_t)r0 * SELCAP + t];
      m1 = Mmat[(size_t)r1 * SELCAP + t];
      m2 = Mmat[(size_t)r2 * SELCAP + t];
      m3 = Mmat[(size_t)r3 * SELCAP + t];
    }
    axc += w0 * x0 + w1 * x1 + w2 * x2 + w3 * x3;
    aco += w0 * m0 + w1 * m1 + w2 * m2 + w3 * m3;
  }
  for (; e < tot; ++e) {
    int rn = cn[e];
    float w = cw[e];
    axc += w * x[(size_t)rn * FD + t];
    if (act) aco += w * Mmat[(size_t)rn * SELCAP + t];
  }
  if (act) row[sel_list[b * SELCAP + t]] = floorf(aco * 10000.0f) / 10000.0f;
  __builtin_nontemporal_store(axc, &xc[(size_t)rm * FD + t]);
  __syncthreads();
  f4* dst = (f4*)(coarse + (size_t)rm * NN);
  const f4* src = (const f4*)row;
#pragma unroll
  for (int j = 0; j < NN / 4 / 256; ++j)
    __builtin_nontemporal_store(src[t + j * 256], &dst[t + j * 256]);  // stream coarse out
}

extern "C" void kernel_launch(void* const* d_in, const int* in_sizes, int n_in,
                              void* d_out, int out_size, void* d_ws, size_t ws_size,
                              hipStream_t stream) {
  (void)in_sizes; (void)n_in; (void)ws_size; (void)out_size;
  const float* x = (const float*)d_in[0];
  const float* adj = (const float*)d_in[1];
  const float* W = (const float*)d_in[2];
  const float* bptr = (const float*)d_in[3];

  float* out = (float*)d_out;
  const size_t XC_SZ = (size_t)BB * NN * FD;   // 4,194,304
  const size_t CO_SZ = (size_t)BB * NN * NN;   // 33,554,432
  const size_t S_SZ  = (size_t)BB * NN * NN;   // 33,554,432
  float* out_xc = out;
  float* out_co = out + XC_SZ;
  float* out_S  = out + XC_SZ + CO_SZ;
  float* out_ti = out + XC_SZ + CO_SZ + S_SZ;  // topi as float (written fully by k_rank)

  char* w = (char*)d_ws;
  int2*  ell     = (int2*)w;  w += (size_t)BB * NN * CAP * 8;
  float* Sc      = (float*)w; w += (size_t)BB * NN * SELCAP * 4;
  float* Mmat    = (float*)w; w += (size_t)BB * NN * SELCAP * 4;
  int2*  seldg   = (int2*)w;  w += (size_t)BB * NN * 8;
  int*   ell_cnt = (int*)w;   w += (size_t)BB * NN * 4;
  float* dg      = (float*)w; w += (size_t)BB * NN * 4;
  float* dgy     = (float*)w; w += (size_t)BB * NN * 4;
  float* alpha   = (float*)w; w += (size_t)BB * NN * 4;
  float* dginv   = (float*)w; w += (size_t)BB * NN * 4;
  float* cutv    = (float*)w; w += (size_t)BB * 4;
  int*   sel_cnt = (int*)w;   w += (size_t)BB * 4;
  int*   sel_list= (int*)w;   w += (size_t)BB * SELCAP * 4;

  // every output byte written by kernels: xc+coarse by k_epi2, S by k_Ms, topi by k_rank
  k_spy<<<BB * NN, 256, 0, stream>>>(adj, x, W, ell, ell_cnt, dg, dgy);
  k_alpha<<<BB * NN / 4, 256, 0, stream>>>(ell, ell_cnt, dg, dgy, bptr, alpha);
  k_rank<<<BB * 8, 256, 0, stream>>>(alpha, cutv, out_ti, sel_cnt);
  k_selcut<<<BB * NN / 256, 256, 0, stream>>>(alpha, cutv, dg, seldg, sel_list, sel_cnt);
  k_sc<<<BB * NN / 4, 256, 0, stream>>>(ell, ell_cnt, dg, seldg, sel_cnt, dginv, Sc);
  k_Ms<<<BB * NN, 256, 0, stream>>>(ell, ell_cnt, sel_cnt, seldg, dginv, Sc, Mmat, out_S);
  k_epi2<<<BB * NN, 256, 0, stream>>>(x, ell, ell_cnt, seldg, dginv,
                                      sel_list, sel_cnt, Mmat, out_xc, out_co);
}

// Round 3
// 480.663 us; speedup vs baseline: 1.0755x; 1.0531x over previous
//
#include <hip/hip_runtime.h>
#include <cstdint>
#include <cstddef>

#define BB 8
#define NN 2048
#define FD 256
#define KK 205      // int(2048*0.1)+1
#define CAP 96      // max nnz per adj row (mean ~41, P(>96) ~ 1e-15)
#define SELCAP 256  // max selected columns (nsel ~205; clamped if ever exceeded)

typedef float f4 __attribute__((ext_vector_type(4)));  // native vec4: valid for nontemporal builtins

// Packed ELL entry: x = column index, y = __float_as_int(value)
// Packed sel entry: x = __float_as_int(dg*cutA), y = selidx

// ---------- fused: ELL sparsify of adj (ballot compaction) + row sum + dg + y = x.W + dgy ----------
__global__ __launch_bounds__(256) void k_spy(const float* __restrict__ adj, const float* __restrict__ x,
                                             const float* __restrict__ W, int2* __restrict__ ell,
                                             int* __restrict__ ell_cnt, float* __restrict__ dg,
                                             float* __restrict__ dgy) {
  int r = blockIdx.x;  // b*NN + n
  const f4* arow4 = (const f4*)(adj + (size_t)r * NN);
  int t = threadIdx.x;
  int lane = t & 63, wv = t >> 6;
  __shared__ int counter;
  __shared__ float wsum[4], wy[4];
  if (t == 0) counter = 0;
  __syncthreads();
  size_t base = (size_t)r * CAP;
  unsigned long long lmask = (1ull << lane) - 1;   // lane<=63 -> no UB
  float ls = 0.f;
#pragma unroll
  for (int j = 0; j < 2; ++j) {
    int i4 = t + j * 256;
    f4 v = __builtin_nontemporal_load(&arow4[i4]);  // read-once stream: don't pollute L2
    int m0 = i4 * 4;
#pragma unroll
    for (int c = 0; c < 4; ++c) {
      float val = v[c];
      unsigned long long mk = __ballot(val != 0.f);
      if (mk) {
        int wbase = 0;
        if (lane == 0) wbase = atomicAdd(&counter, (int)__popcll(mk));
        wbase = __shfl(wbase, 0);                  // one atomic per wave per component
        if (val != 0.f) {
          int p = wbase + (int)__popcll(mk & lmask);
          if (p < CAP) ell[base + p] = make_int2(m0 + c, __float_as_int(val));
        }
      }
      ls += val;                                   // val==0 adds nothing
    }
  }
#pragma unroll
  for (int off = 32; off > 0; off >>= 1) ls += __shfl_down(ls, off);
  if (lane == 0) wsum[wv] = ls;
  float xv = x[(size_t)r * FD + t] * W[t];
#pragma unroll
  for (int off = 32; off > 0; off >>= 1) xv += __shfl_down(xv, off);
  if (lane == 0) wy[wv] = xv;
  __syncthreads();
  if (t == 0) {
    int tot = counter; if (tot > CAP) tot = CAP;
    ell_cnt[r] = tot;
    float rs = wsum[0] + wsum[1] + wsum[2] + wsum[3];
    float d = 1.0f / sqrtf(1.0f + rs);  // A_hat row sum = 1 + adj row sum >= 1 (clip is a no-op)
    dg[r] = d;
    dgy[r] = d * (wy[0] + wy[1] + wy[2] + wy[3]);  // fused product: one gather in k_alpha
  }
}

// ---------- alpha[b,n] = sigmoid((dg[n]*(sum_m A_hat[n,m]*dg[m]*y[m]) + b)^2) ----------
__global__ __launch_bounds__(256) void k_alpha(const int2* __restrict__ ell, const int* __restrict__ ell_cnt,
                                               const float* __restrict__ dg, const float* __restrict__ dgy,
                                               const float* __restrict__ bptr, float* __restrict__ alpha) {
  int lane = threadIdx.x & 63, wv = threadIdx.x >> 6;
  int r = blockIdx.x * 4 + wv;
  int b = r / NN;
  int cnt = ell_cnt[r];
  size_t base = (size_t)r * CAP;
  const float* gyb = dgy + (size_t)b * NN;
  float acc = 0.f;
  for (int j = lane; j < cnt; j += 64) {
    int2 e = ell[base + j];
    acc += __int_as_float(e.y) * gyb[e.x];        // single gather per entry
  }
#pragma unroll
  for (int off = 32; off > 0; off >>= 1) acc += __shfl_down(acc, off);
  if (lane == 0) {
    float dgn = dg[r];
    float z = dgn * (acc + dgy[r]) + bptr[0];     // diag: dgn * (dgn*y[r]) = dgn * dgy[r]
    float t2 = z * z;
    alpha[r] = 1.0f / (1.0f + expf(-t2));
  }
}

// ---------- rank-based exact top-K (ties -> smaller index first, like lax.top_k) ----------
__global__ __launch_bounds__(256) void k_rank(const float* __restrict__ alpha, float* __restrict__ cutv,
                                              float* __restrict__ out_topi, int* __restrict__ sel_cnt) {
  __shared__ unsigned int keys[NN];  // 8 KiB: alpha bits (alpha >= 0.5 > 0 -> bit order == value order)
  int b = blockIdx.x & 7;
  int chunk = blockIdx.x >> 3;
  int t = threadIdx.x;
  if (chunk == 0 && t == 0) sel_cnt[b] = 0;   // replaces the sel_cnt memset dispatch
  const float* ab = alpha + (size_t)b * NN;
  for (int i = t; i < NN; i += 256) keys[i] = __float_as_uint(ab[i]);
  __syncthreads();
  int i = chunk * 256 + t;
  unsigned int ai = keys[i];
  int rank = 0;
  const uint4* k4 = (const uint4*)keys;       // broadcast reads: all lanes same addr, conflict-free
#pragma unroll 4
  for (int j4 = 0; j4 < NN / 4; ++j4) {
    uint4 v = k4[j4];
    int j = j4 * 4;
    rank += (v.x > ai) || (v.x == ai && (j + 0) < i);
    rank += (v.y > ai) || (v.y == ai && (j + 1) < i);
    rank += (v.z > ai) || (v.z == ai && (j + 2) < i);
    rank += (v.w > ai) || (v.w == ai && (j + 3) < i);
  }
  if (rank < KK) out_topi[(size_t)b * KK + rank] = (float)i;
  if (rank == KK - 1) cutv[b] = __uint_as_float(ai);
}

// ---------- cut_alpha + selected compaction (wave-aggregated atomics) + packed {dgca, selidx} ----------
__global__ __launch_bounds__(256) void k_selcut(const float* __restrict__ alpha, const float* __restrict__ cutv,
                                                const float* __restrict__ dg, int2* __restrict__ seldg,
                                                int* __restrict__ sel_list, int* __restrict__ sel_cnt) {
  int t = threadIdx.x;
  int r = blockIdx.x * 256 + t;
  int b = r >> 11, n = r & (NN - 1);              // batch is block-uniform (2048/256 = 8 blocks/batch)
  int lane = t & 63;
  float ca = fmaxf(alpha[r] + 1e-7f - cutv[b], 0.0f);
  bool on = ca > 0.f;
  unsigned long long mk = __ballot(on);
  int s = -1;
  if (mk) {
    int wbase = 0;
    if (lane == 0) wbase = atomicAdd(&sel_cnt[b], (int)__popcll(mk));
    wbase = __shfl(wbase, 0);                     // one global atomic per wave (was one per thread)
    if (on) {
      unsigned long long lm = (1ull << lane) - 1;
      s = wbase + (int)__popcll(mk & lm);
      if (s < SELCAP) sel_list[b * SELCAP + s] = n; else s = -1;
    }
  }
  seldg[r] = make_int2(__float_as_int(dg[r] * ca), s);  // one 8B gather serves downstream
}

// ---------- wave-per-row Sc builder + dginv (no __syncthreads) ----------
__global__ __launch_bounds__(256) void k_sc(const int2* __restrict__ ell, const int* __restrict__ ell_cnt,
                                            const float* __restrict__ dg, const int2* __restrict__ seldg,
                                            const int* __restrict__ sel_cnt,
                                            float* __restrict__ dginv, float* __restrict__ Sc) {
  int lane = threadIdx.x & 63, wv = threadIdx.x >> 6;
  int r = blockIdx.x * 4 + wv;       // one wave per row
  int b = r >> 11, n = r & (NN - 1);
  __shared__ float scrow[4][SELCAP]; // per-wave slice: wave-coherent LDS, no barrier needed
  float* sc = scrow[wv];
#pragma unroll
  for (int j = lane; j < SELCAP; j += 64) sc[j] = 0.f;
  int cnt = ell_cnt[r];
  size_t base = (size_t)r * CAP;
  float dgn = dg[r];
  const int2* sdb = seldg + (size_t)b * NN;
  // CAP=96 <= 128: at most 2 entries per lane
  float t0 = 0.f, t1 = 0.f;
  int s0 = -1, s1 = -1;
  if (lane < cnt) {
    int2 e = ell[base + lane];
    int2 sd = sdb[e.x];
    t0 = dgn * __int_as_float(e.y) * __int_as_float(sd.x);  // same mult order as before
    s0 = sd.y;
  }
  if (lane + 64 < cnt) {
    int2 e = ell[base + lane + 64];
    int2 sd = sdb[e.x];
    t1 = dgn * __int_as_float(e.y) * __int_as_float(sd.x);
    s1 = sd.y;
  }
  float part = t0 + t1;
#pragma unroll
  for (int off = 32; off > 0; off >>= 1) part += __shfl_down(part, off);
  part = __shfl(part, 0);                             // broadcast row sum
  int2 sdn = sdb[n];                                  // same addr across wave -> broadcast load
  float diag = dgn * __int_as_float(sdn.x);           // dgn * dg[n]*cutA[n]
  float rho = part + diag;                            // L1 row sum (all >= 0)
  float inv = (cnt > 0) ? (1.0f / fmaxf(rho, 1e-12f)) : 0.f;  // mask * normalize
  if (lane == 0) dginv[r] = dgn * inv;                // fused product for k_Ms / k_epi2
  if (s0 >= 0) sc[s0] = t0 * inv;                     // in-wave LDS scatter
  if (s1 >= 0) sc[s1] = t1 * inv;
  int nsel = sel_cnt[b]; if (nsel > SELCAP) nsel = SELCAP;
  float dv = diag * inv;
  for (int p = lane; p < nsel; p += 64) {             // compiler orders ds_read after ds_write (same wave)
    float sv = sc[p];
    if (p == sdn.y) sv += dv;                         // diagonal lands in compact row iff n selected
    Sc[(size_t)r * SELCAP + p] = sv;
  }
}

// ---------- fused: M[n,:] = adj.Sc  +  dense S row -> out_S  +  zero coarse/xc for UNSELECTED rows ----------
// All streaming stores (S 134MB + coarse-zeros 120MB + xc-zeros 15MB) live in this kernel, hiding the
// L2 Sc-gather latency; k_epi2 then only touches selected rows.
__global__ __launch_bounds__(256) void k_Ms(const int2* __restrict__ ell, const int* __restrict__ ell_cnt,
                                            const int* __restrict__ sel_cnt, const int2* __restrict__ seldg,
                                            const float* __restrict__ dginv, const float* __restrict__ Sc,
                                            float* __restrict__ Mmat, float* __restrict__ outS,
                                            float* __restrict__ xc, float* __restrict__ coarse) {
  int b = blockIdx.x & 7;           // batch -> XCD: Sc[b] (~0.8 MB) stays L2-resident
  int n = blockIdx.x >> 3;
  int r = b * NN + n;
  int t = threadIdx.x;
  __shared__ float row[NN];         // 8 KiB dense S row
  __shared__ int srk[CAP];
  __shared__ float sav[CAP];
#pragma unroll
  for (int j = 0; j < NN / 256; ++j) row[t + j * 256] = 0.f;
  int cnt = ell_cnt[r];
  size_t base = (size_t)r * CAP;
  float dinv = dginv[r];            // dg[r] * inv_r  (0 if cnt==0 -> zero S row)
  const int2* sdb = seldg + (size_t)b * NN;
  for (int e = t; e < cnt; e += 256) {
    int2 p = ell[base + e];
    srk[e] = b * NN + p.x;
    float v = __int_as_float(p.y);
    sav[e] = v;
    row[p.x] = dinv * v * __int_as_float(sdb[p.x].x);  // distinct cols -> conflict-free scatter
  }
  __syncthreads();
  int2 sdn = sdb[n];
  float dv = dinv * __int_as_float(sdn.x);             // diagonal S[n,n] contribution
  f4* dst = (f4*)(outS + (size_t)r * NN);
  const f4* src = (const f4*)row;
#pragma unroll
  for (int j = 0; j < NN / 4 / 256; ++j) {
    int idx = t + j * 256;
    f4 v = src[idx];
    int b4 = idx * 4;                                  // fold diag branchlessly (handles adj self-loop: +=)
    v[0] += (b4 + 0 == n) ? dv : 0.f;
    v[1] += (b4 + 1 == n) ? dv : 0.f;
    v[2] += (b4 + 2 == n) ? dv : 0.f;
    v[3] += (b4 + 3 == n) ? dv : 0.f;
    __builtin_nontemporal_store(v, &dst[idx]);         // stream S out; stores don't stall the gathers below
  }
  if (sdn.y < 0) {                                     // unselected row: its coarse/xc rows are all zero
    f4 z = (f4)(0.f);
    if (t < FD / 4) __builtin_nontemporal_store(z, &((f4*)(xc + (size_t)r * FD))[t]);
    f4* dco = (f4*)(coarse + (size_t)r * NN);
    __builtin_nontemporal_store(z, &dco[t]);
    __builtin_nontemporal_store(z, &dco[t + 256]);
  }
  int nsel = sel_cnt[b]; if (nsel > SELCAP) nsel = SELCAP;
  if (t >= nsel) return;            // no barriers below; trims ~20% of gather traffic
  float a0 = 0.f, a1 = 0.f, a2 = 0.f, a3 = 0.f, a4 = 0.f, a5 = 0.f, a6 = 0.f, a7 = 0.f;
  int e = 0;
  for (; e + 8 <= cnt; e += 8) {    // 8 loads in flight per iteration
    a0 += sav[e + 0] * Sc[(size_t)srk[e + 0] * SELCAP + t];
    a1 += sav[e + 1] * Sc[(size_t)srk[e + 1] * SELCAP + t];
    a2 += sav[e + 2] * Sc[(size_t)srk[e + 2] * SELCAP + t];
    a3 += sav[e + 3] * Sc[(size_t)srk[e + 3] * SELCAP + t];
    a4 += sav[e + 4] * Sc[(size_t)srk[e + 4] * SELCAP + t];
    a5 += sav[e + 5] * Sc[(size_t)srk[e + 5] * SELCAP + t];
    a6 += sav[e + 6] * Sc[(size_t)srk[e + 6] * SELCAP + t];
    a7 += sav[e + 7] * Sc[(size_t)srk[e + 7] * SELCAP + t];
  }
  for (; e < cnt; ++e) a0 += sav[e] * Sc[(size_t)srk[e] * SELCAP + t];
  Mmat[(size_t)r * SELCAP + t] = ((a0 + a1) + (a2 + a3)) + ((a4 + a5) + (a6 + a7));
}

// ---------- epilogue over SELECTED rows only (grid = 8 x SELCAP via sel_list indirection) ----------
__global__ __launch_bounds__(256) void k_epi2(const float* __restrict__ x, const int2* __restrict__ ell,
                                              const int* __restrict__ ell_cnt, const int2* __restrict__ seldg,
                                              const float* __restrict__ dginv, const int* __restrict__ sel_list,
                                              const int* __restrict__ sel_cnt, const float* __restrict__ Mmat,
                                              float* __restrict__ xc, float* __restrict__ coarse) {
  int b = blockIdx.x & 7;           // batch -> XCD: x[b], Mmat[b] (~2 MB each) stay L2-resident
  int si = blockIdx.x >> 3;
  int nsel = sel_cnt[b]; if (nsel > SELCAP) nsel = SELCAP;
  if (si >= nsel) return;           // ~50 no-op blocks per batch
  int m = sel_list[b * SELCAP + si];
  int rm = b * NN + m;
  int t = threadIdx.x;
  __shared__ float row[NN];         // 8 KiB coarse row
  __shared__ int cn[CAP + 1];
  __shared__ float cw[CAP + 1];
  int2 sd_m = seldg[rm];
  int cnt = ell_cnt[rm];
#pragma unroll
  for (int j = 0; j < NN / 256; ++j) row[t + j * 256] = 0.f;
  {
    float dgca_m = __int_as_float(sd_m.x);           // dg[m]*cutA[m]
    // column m of S == row m of adj (exact symmetry) plus the diagonal (+1) entry
    for (int j = t; j <= cnt; j += 256) {
      if (j < cnt) {
        int2 e = ell[(size_t)rm * CAP + j];
        cn[j] = b * NN + e.x;
        cw[j] = __int_as_float(e.y) * dgca_m * dginv[b * NN + e.x];  // single gather per entry
      } else {
        cn[j] = rm;
        cw[j] = dgca_m * dginv[rm];
      }
    }
  }
  __syncthreads();
  bool act = t < nsel;              // only these lanes' aco is ever consumed
  float axc = 0.f, aco = 0.f;
  int tot = cnt + 1;
  int e = 0;
  for (; e + 4 <= tot; e += 4) {    // 4-way MLP: up to 8 independent loads in flight
    int r0 = cn[e + 0], r1 = cn[e + 1], r2 = cn[e + 2], r3 = cn[e + 3];
    float w0 = cw[e + 0], w1 = cw[e + 1], w2 = cw[e + 2], w3 = cw[e + 3];
    float x0 = x[(size_t)r0 * FD + t];
    float x1 = x[(size_t)r1 * FD + t];
    float x2 = x[(size_t)r2 * FD + t];
    float x3 = x[(size_t)r3 * FD + t];
    float m0 = 0.f, m1 = 0.f, m2 = 0.f, m3 = 0.f;
    if (act) {
      m0 = Mmat[(size_t)r0 * SELCAP + t];
      m1 = Mmat[(size_t)r1 * SELCAP + t];
      m2 = Mmat[(size_t)r2 * SELCAP + t];
      m3 = Mmat[(size_t)r3 * SELCAP + t];
    }
    axc += w0 * x0 + w1 * x1 + w2 * x2 + w3 * x3;
    aco += w0 * m0 + w1 * m1 + w2 * m2 + w3 * m3;
  }
  for (; e < tot; ++e) {
    int rn = cn[e];
    float w = cw[e];
    axc += w * x[(size_t)rn * FD + t];
    if (act) aco += w * Mmat[(size_t)rn * SELCAP + t];
  }
  if (act) row[sel_list[b * SELCAP + t]] = floorf(aco * 10000.0f) / 10000.0f;
  __builtin_nontemporal_store(axc, &xc[(size_t)rm * FD + t]);
  __syncthreads();
  f4* dst = (f4*)(coarse + (size_t)rm * NN);
  const f4* src = (const f4*)row;
#pragma unroll
  for (int j = 0; j < NN / 4 / 256; ++j)
    __builtin_nontemporal_store(src[t + j * 256], &dst[t + j * 256]);  // stream coarse out
}

extern "C" void kernel_launch(void* const* d_in, const int* in_sizes, int n_in,
                              void* d_out, int out_size, void* d_ws, size_t ws_size,
                              hipStream_t stream) {
  (void)in_sizes; (void)n_in; (void)ws_size; (void)out_size;
  const float* x = (const float*)d_in[0];
  const float* adj = (const float*)d_in[1];
  const float* W = (const float*)d_in[2];
  const float* bptr = (const float*)d_in[3];

  float* out = (float*)d_out;
  const size_t XC_SZ = (size_t)BB * NN * FD;   // 4,194,304
  const size_t CO_SZ = (size_t)BB * NN * NN;   // 33,554,432
  const size_t S_SZ  = (size_t)BB * NN * NN;   // 33,554,432
  float* out_xc = out;
  float* out_co = out + XC_SZ;
  float* out_S  = out + XC_SZ + CO_SZ;
  float* out_ti = out + XC_SZ + CO_SZ + S_SZ;  // topi as float (written fully by k_rank)

  char* w = (char*)d_ws;
  int2*  ell     = (int2*)w;  w += (size_t)BB * NN * CAP * 8;
  float* Sc      = (float*)w; w += (size_t)BB * NN * SELCAP * 4;
  float* Mmat    = (float*)w; w += (size_t)BB * NN * SELCAP * 4;
  int2*  seldg   = (int2*)w;  w += (size_t)BB * NN * 8;
  int*   ell_cnt = (int*)w;   w += (size_t)BB * NN * 4;
  float* dg      = (float*)w; w += (size_t)BB * NN * 4;
  float* dgy     = (float*)w; w += (size_t)BB * NN * 4;
  float* alpha   = (float*)w; w += (size_t)BB * NN * 4;
  float* dginv   = (float*)w; w += (size_t)BB * NN * 4;
  float* cutv    = (float*)w; w += (size_t)BB * 4;
  int*   sel_cnt = (int*)w;   w += (size_t)BB * 4;
  int*   sel_list= (int*)w;   w += (size_t)BB * SELCAP * 4;

  // every output byte written exactly once: xc+coarse by k_Ms (unselected) / k_epi2 (selected),
  // S by k_Ms, topi by k_rank
  k_spy<<<BB * NN, 256, 0, stream>>>(adj, x, W, ell, ell_cnt, dg, dgy);
  k_alpha<<<BB * NN / 4, 256, 0, stream>>>(ell, ell_cnt, dg, dgy, bptr, alpha);
  k_rank<<<BB * 8, 256, 0, stream>>>(alpha, cutv, out_ti, sel_cnt);
  k_selcut<<<BB * NN / 256, 256, 0, stream>>>(alpha, cutv, dg, seldg, sel_list, sel_cnt);
  k_sc<<<BB * NN / 4, 256, 0, stream>>>(ell, ell_cnt, dg, seldg, sel_cnt, dginv, Sc);
  k_Ms<<<BB * NN, 256, 0, stream>>>(ell, ell_cnt, sel_cnt, seldg, dginv, Sc, Mmat,
                                    out_S, out_xc, out_co);
  k_epi2<<<BB * SELCAP, 256, 0, stream>>>(x, ell, ell_cnt, seldg, dginv,
                                          sel_list, sel_cnt, Mmat, out_xc, out_co);
}